// Round 5
// baseline (5267.036 us; speedup 1.0000x reference)
//
#include <hip/hip_runtime.h>
#include <hip/hip_fp16.h>

// ---------------------------------------------------------------------------
// 2-layer LSTM (T=512, B=128, H=512) + linear head, persistent-kernel design.
// Round 5: round-4 structure + value-verified readback before flag release.
//  - Producer threads re-load the 8B they just stored (relaxed agent-scope,
//    LLC-direct) and spin until the bits match -> data PROVEN readable at the
//    coherency point before any consumer flag is raised. Closes the
//    vmcnt-ack vs LLC-readability window exposed by fast private flag lines.
//  - Private per-consumer flag lines (no LLC same-line contention),
//    per-wave polling, batched A-fragment loads, linear head off-path.
// ---------------------------------------------------------------------------

#define HDIM   512
#define TSTEPS 512
#define BATCH  128
#define DIN    5
#define NGRP   4
#define MGRP   32
#define NB1    16
#define NB2    32
#define RING   16

#define OFF_W1 0u            // packed layer1 weights: 16 blocks * 128KB = 2MB
#define OFF_W2 2097152u      // packed layer2 weights: 32 blocks * 128KB = 4MB
#define OFF_H1 6291456u      // h1 ring: 4 * 16 * 32 * 512 fp16 = 2MB
#define OFF_H2 8388608u      // h2 ring: 4 * 2 * 32 * 512 fp16 = 256KB
#define OFF_F1 8650752u      // flags1 repl: 4 grp * 48 consumers * 16 u32 = 12KB
#define OFF_F2 8663040u      // flags2 repl: 4 grp * 48 consumers * 32 u32 = 24KB
#define WS_END 8687616u

#define L1_HALF 31   // LDS-resident b-rows per hh half (of 64) in layer1
#define L2_HALF 27   // LDS-resident b-rows per kh half (of 64) in layer2

typedef _Float16 half8 __attribute__((ext_vector_type(8)));
typedef float    floatx4 __attribute__((ext_vector_type(4)));

__device__ __forceinline__ float sigf(float v) { return 1.0f / (1.0f + __expf(-v)); }

// 16B A-fragment read: two cache-bypassing relaxed 8B atomic loads (to LLC).
__device__ __forceinline__ half8 ring_ld16(const _Float16* p) {
  union { unsigned long long u[2]; half8 h; } r;
  unsigned long long* q = (unsigned long long*)p;
  r.u[0] = __hip_atomic_load(q,     __ATOMIC_RELAXED, __HIP_MEMORY_SCOPE_AGENT);
  r.u[1] = __hip_atomic_load(q + 1, __ATOMIC_RELAXED, __HIP_MEMORY_SCOPE_AGENT);
  return r.h;
}
__device__ __forceinline__ void ring_st8(unsigned long long* p, unsigned long long v) {
  __hip_atomic_store(p, v, __ATOMIC_RELAXED, __HIP_MEMORY_SCOPE_AGENT);
}
// Spin until the 8B at p reads back as v (proves the line is READABLE at the
// LLC coherency point; per-line serialization then guarantees all later
// readers see it).
__device__ __forceinline__ void verify8(unsigned long long* p, unsigned long long v) {
  while (__hip_atomic_load(p, __ATOMIC_RELAXED, __HIP_MEMORY_SCOPE_AGENT) != v)
    ;
}
__device__ __forceinline__ void flag_st(unsigned* p, unsigned v) {
  __hip_atomic_store(p, v, __ATOMIC_RELAXED, __HIP_MEMORY_SCOPE_AGENT);
}
// Poll a PRIVATE flag line: lane i (<n, != skip) loads flag i; exit when all
// >= tgt. Only this block's waves touch the line -> no LLC bank contention.
__device__ __forceinline__ void pollN(const unsigned* f, int n, unsigned tgt,
                                      int lane, int skip) {
  for (;;) {
    unsigned v = tgt;
    if (lane < n && lane != skip)
      v = __hip_atomic_load(f + lane, __ATOMIC_RELAXED, __HIP_MEMORY_SCOPE_AGENT);
    if (__all((int)(v >= tgt))) break;
  }
  __asm__ __volatile__("" ::: "memory");
}

// ---------------------------------------------------------------------------
extern "C" __global__ void init_kernel(char* __restrict__ ws, float* __restrict__ out,
                                       const float* __restrict__ blin) {
  unsigned tid = blockIdx.x * 256u + threadIdx.x;
  unsigned nz = (WS_END - OFF_H1) / 16u;
  if (tid < nz) ((uint4*)(ws + OFF_H1))[tid] = make_uint4(0, 0, 0, 0);
  if (tid < (unsigned)(BATCH * TSTEPS)) out[tid] = blin[0];
}

// Pack fp32 weights -> fp16 MFMA B-fragment layout (unchanged).
extern "C" __global__ void pack_kernel(const float* __restrict__ Whh1,
                                       const float* __restrict__ Wih2,
                                       const float* __restrict__ Whh2,
                                       char* __restrict__ ws) {
  unsigned tid = blockIdx.x * 256u + threadIdx.x;
  const float* src;
  char* dst;
  if (tid < 131072u) {
    unsigned lane = tid & 63u, ks = (tid >> 6) & 15u, gg = (tid >> 10) & 3u,
             h = (tid >> 12) & 1u, j = tid >> 13;
    unsigned cg = j * 32u + h * 16u + (lane & 15u);
    unsigned row = gg * 512u + cg;
    unsigned k0 = ks * 32u + (lane >> 4) * 8u;
    src = Whh1 + (size_t)row * 512u + k0;
    dst = ws + OFF_W1 + (size_t)tid * 16u;
  } else {
    unsigned t2 = tid - 131072u;
    if (t2 >= 262144u) return;
    unsigned lane = t2 & 63u, ksl = (t2 >> 6) & 15u, gg = (t2 >> 10) & 3u,
             kh = (t2 >> 12) & 1u, j = t2 >> 13;
    unsigned cg = j * 16u + (lane & 15u);
    unsigned row = gg * 512u + cg;
    unsigned kp = kh * 512u + ksl * 32u + (lane >> 4) * 8u;
    src = (kp < 512u) ? (Wih2 + (size_t)row * 512u + kp)
                      : (Whh2 + (size_t)row * 512u + (kp - 512u));
    dst = ws + OFF_W2 + (size_t)t2 * 16u;
  }
  float4 lo = ((const float4*)src)[0];
  float4 hi = ((const float4*)src)[1];
  _Float16 v[8] = {(_Float16)lo.x, (_Float16)lo.y, (_Float16)lo.z, (_Float16)lo.w,
                   (_Float16)hi.x, (_Float16)hi.y, (_Float16)hi.z, (_Float16)hi.w};
  *(uint4*)dst = *(const uint4*)v;
}

// ---------------------------------------------------------------------------
extern "C" __global__ __launch_bounds__(256) void lstm_persist(
    const float* __restrict__ x,
    const float* __restrict__ Wih1,
    const float* __restrict__ bih1, const float* __restrict__ bhh1,
    const float* __restrict__ bih2, const float* __restrict__ bhh2,
    const float* __restrict__ Wlin,
    float* __restrict__ out,
    char* __restrict__ ws) {
  __shared__ char smem[65536];

  const int blk = blockIdx.x;
  const int xcd = blk & 7;
  const int slot = blk >> 3;
  const int tid = threadIdx.x;
  const int wave = tid >> 6;
  const int lane = tid & 63;
  const int nlane = lane & 15;
  const int quad = lane >> 4;

  _Float16* h1ring = (_Float16*)(ws + OFF_H1);
  _Float16* h2ring = (_Float16*)(ws + OFF_H2);
  unsigned* fl1 = (unsigned*)(ws + OFF_F1);  // [g][consumer 0..47][producer 0..15]
  unsigned* fl2 = (unsigned*)(ws + OFF_F2);  // [g][consumer 0..47][producer 0..31]
  // flags1 consumers: 0..15 = L1 block j ; 16..47 = L2 block j
  // flags2 consumers: 0..31 = L2 block j ; 32..47 = L1 block j (back-pressure)

  if (xcd >= NGRP) {
    // ------------------------------ layer 1 -------------------------------
    const int g = xcd - NGRP;
    const int j = slot;
    if (j >= NB1) return;
    const char* gW = ws + OFF_W1 + (size_t)j * 131072u;
    {
      const uint4* s = (const uint4*)gW;
      uint4* d = (uint4*)smem;
      for (int i = tid; i < 62 * 64; i += 256) {
        int drow = i >> 6, c = i & 63;
        int srow = (drow < L1_HALF) ? drow : (64 + drow - L1_HALF);
        d[i] = s[srow * 64 + c];
      }
    }
    __syncthreads();
    _Float16* tile = (_Float16*)(smem + 63488);

    const int mt = wave >> 1;  // batch half (16 rows)
    const int hh = wave & 1;   // column half (16 cols)
    const int cg = j * 32 + hh * 16 + nlane;
    const unsigned* myf1 = fl1 + ((size_t)g * 48 + j) * 16;
    const unsigned* myf2 = fl2 + ((size_t)g * 48 + 32 + j) * 32;
    unsigned* stbase = fl1 + (size_t)g * 48 * 16 + j;  // + consumer*16
    _Float16* ring = h1ring + (size_t)g * (RING * MGRP * HDIM);

    float bias_r[4], wih[4][5];
    for (int gg = 0; gg < 4; ++gg) {
      int row = gg * 512 + cg;
      bias_r[gg] = bih1[row] + bhh1[row];
      for (int k = 0; k < 5; ++k) wih[gg][k] = Wih1[row * 5 + k];
    }
    float cstate[4] = {};

    for (int t = 0; t < TSTEPS; ++t) {
      // peers' h1(t-1) visible?  (private line, own entry skipped)
      if (t) pollN(myf1, NB1, (unsigned)t, lane, j);
      // amortized ring back-pressure (overwrite slot t%16 = h1(t-16)):
      if ((t & 7) == 0 && t >= 16) pollN(myf2, NB2, (unsigned)(t - 8), lane, -1);

      // batched A-fragment loads (32 independent 8B LLC loads -> pipeline)
      const _Float16* aprev =
          ring + (size_t)((t + RING - 1) % RING) * (MGRP * HDIM) +
          mt * 16 * HDIM + nlane * HDIM + quad * 8;
      half8 a[16];
#pragma unroll
      for (int ks = 0; ks < 16; ++ks) a[ks] = ring_ld16(aprev + ks * 32);

      // acc init = bias + x_t @ W_ih1^T (fp32, K=5) -- hides A-load latency
      float xr[4][5];
#pragma unroll
      for (int r = 0; r < 4; ++r) {
        int b = g * MGRP + mt * 16 + quad * 4 + r;
        const float* xp = x + ((size_t)t * BATCH + b) * DIN;
#pragma unroll
        for (int k = 0; k < 5; ++k) xr[r][k] = xp[k];
      }
      floatx4 acc[4];
#pragma unroll
      for (int gg = 0; gg < 4; ++gg) {
#pragma unroll
        for (int r = 0; r < 4; ++r) {
          float s = bias_r[gg];
#pragma unroll
          for (int k = 0; k < 5; ++k) s += xr[r][k] * wih[gg][k];
          acc[gg][r] = s;
        }
      }
#pragma unroll
      for (int ks = 0; ks < 16; ++ks) {
#pragma unroll
        for (int gg = 0; gg < 4; ++gg) {
          half8 b;
          if (gg * 16 + ks < L1_HALF)
            b = *(const half8*)(smem + ((hh * L1_HALF + gg * 16 + ks) * 64 + lane) * 16);
          else
            b = *(const half8*)(gW + (size_t)((hh * 64 + gg * 16 + ks) * 64 + lane) * 16);
          acc[gg] = __builtin_amdgcn_mfma_f32_16x16x32_f16(a[ks], b, acc[gg], 0, 0, 0);
        }
      }
      // gates -> LDS transpose tile (32 x 32 fp16)
#pragma unroll
      for (int r = 0; r < 4; ++r) {
        float iv = acc[0][r], fv = acc[1][r], gv = acc[2][r], ov = acc[3][r];
        float cn = sigf(fv) * cstate[r] + sigf(iv) * tanhf(gv);
        float hn = sigf(ov) * tanhf(cn);
        cstate[r] = cn;
        tile[(mt * 16 + quad * 4 + r) * 32 + hh * 16 + nlane] = (_Float16)hn;
      }
      __syncthreads();
      // ring store + value-verified readback
      _Float16* hout = ring + (size_t)(t % RING) * (MGRP * HDIM);
      unsigned long long v =
          *(const unsigned long long*)(tile + (tid >> 3) * 32 + (tid & 7) * 4);
      unsigned long long* dst =
          (unsigned long long*)(hout + (tid >> 3) * HDIM + j * 32 + (tid & 7) * 4);
      ring_st8(dst, v);
      __syncthreads();  // drains vmcnt (stores issued & ack'd)
      verify8(dst, v);  // proven readable at LLC
      __syncthreads();
      // broadcast flag to the 48 private consumer lines (fire-and-forget)
      if (tid < 48) flag_st(stbase + tid * 16, (unsigned)(t + 1));
    }
  } else {
    // ------------------------------ layer 2 -------------------------------
    const int g = xcd;
    const int j = slot;
    const char* gW = ws + OFF_W2 + (size_t)j * 131072u;
    {
      const uint4* s = (const uint4*)gW;
      uint4* d = (uint4*)smem;
      for (int i = tid; i < 54 * 64; i += 256) {
        int drow = i >> 6, c = i & 63;
        int srow = (drow < L2_HALF) ? drow : (64 + drow - L2_HALF);
        d[i] = s[srow * 64 + c];
      }
    }
    __syncthreads();
    floatx4* pbase = (floatx4*)(smem + 55296);
    _Float16* tile2 = (_Float16*)(smem + 63488);

    const int kh = wave & 1;   // 0 -> h1(t) (W_ih2 half), 1 -> h2(t-1) (W_hh2 half)
    const int mt = wave >> 1;  // batch half
    const int cg = j * 16 + nlane;
    const unsigned* myf1 = fl1 + ((size_t)g * 48 + 16 + j) * 16;
    const unsigned* myf2 = fl2 + ((size_t)g * 48 + j) * 32;
    unsigned* stbase = fl2 + (size_t)g * 48 * 32 + j;  // + consumer*32
    const _Float16* h1rd = h1ring + (size_t)g * (RING * MGRP * HDIM);
    _Float16* ring2 = h2ring + (size_t)g * (2 * MGRP * HDIM);

    float bias_r[4];
    for (int gg = 0; gg < 4; ++gg) {
      int row = gg * 512 + cg;
      bias_r[gg] = bih2[row] + bhh2[row];
    }
    const float wl = Wlin[cg];
    float cstate[4] = {};

    for (int t = 0; t < TSTEPS; ++t) {
      // kh0 needs h1(t) (f1 >= t+1); kh1 needs peers' h2(t-1) (f2 >= t)
      if (kh == 0) pollN(myf1, NB1, (unsigned)(t + 1), lane, -1);
      else if (t) pollN(myf2, NB2, (unsigned)t, lane, j);

      const _Float16* abase = (kh == 0)
          ? h1rd + (size_t)(t % RING) * (MGRP * HDIM) + mt * 16 * HDIM
          : ring2 + (size_t)((t + 1) & 1) * (MGRP * HDIM) + mt * 16 * HDIM;
      half8 a[16];
#pragma unroll
      for (int ksl = 0; ksl < 16; ++ksl)
        a[ksl] = ring_ld16(abase + nlane * HDIM + ksl * 32 + quad * 8);

      floatx4 acc[4];
#pragma unroll
      for (int gg = 0; gg < 4; ++gg)
        acc[gg] = (kh == 0)
            ? (floatx4){bias_r[gg], bias_r[gg], bias_r[gg], bias_r[gg]}
            : (floatx4){0.f, 0.f, 0.f, 0.f};
#pragma unroll
      for (int ksl = 0; ksl < 16; ++ksl) {
#pragma unroll
        for (int gg = 0; gg < 4; ++gg) {
          half8 b;
          if (gg * 16 + ksl < L2_HALF)
            b = *(const half8*)(smem + ((kh * L2_HALF + gg * 16 + ksl) * 64 + lane) * 16);
          else
            b = *(const half8*)(gW + (size_t)((kh * 64 + gg * 16 + ksl) * 64 + lane) * 16);
          acc[gg] = __builtin_amdgcn_mfma_f32_16x16x32_f16(a[ksl], b, acc[gg], 0, 0, 0);
        }
      }
      if (kh == 1) {
#pragma unroll
        for (int gg = 0; gg < 4; ++gg) pbase[(mt * 4 + gg) * 64 + lane] = acc[gg];
      }
      __syncthreads();
      float red[4];
      if (kh == 0) {
#pragma unroll
        for (int gg = 0; gg < 4; ++gg) acc[gg] += pbase[(mt * 4 + gg) * 64 + lane];
#pragma unroll
        for (int r = 0; r < 4; ++r) {
          float iv = acc[0][r], fv = acc[1][r], gv = acc[2][r], ov = acc[3][r];
          float cn = sigf(fv) * cstate[r] + sigf(iv) * tanhf(gv);
          float hn = sigf(ov) * tanhf(cn);
          cstate[r] = cn;
          tile2[(mt * 16 + quad * 4 + r) * 16 + nlane] = (_Float16)hn;
          red[r] = wl * hn;
        }
      }
      __syncthreads();
      // ring store + value-verified readback (tid < 128 cover the 32x16 tile)
      unsigned long long v = 0;
      unsigned long long* dst = nullptr;
      if (tid < 128) {
        v = *(const unsigned long long*)(tile2 + (tid >> 2) * 16 + (tid & 3) * 4);
        dst = (unsigned long long*)(ring2 + (size_t)(t & 1) * (MGRP * HDIM) +
                                    (tid >> 2) * HDIM + j * 16 + (tid & 3) * 4);
        ring_st8(dst, v);
      }
      __syncthreads();  // drains vmcnt
      if (tid < 128) verify8(dst, v);  // proven readable at LLC
      __syncthreads();
      // broadcast flag to the 48 private consumer lines (fire-and-forget)
      if (tid < 48) flag_st(stbase + tid * 32, (unsigned)(t + 1));
      // linear head: off the critical path (after flag release)
      if (kh == 0) {
#pragma unroll
        for (int r = 0; r < 4; ++r) {
          float v2 = red[r];
          v2 += __shfl_xor(v2, 1, 64);
          v2 += __shfl_xor(v2, 2, 64);
          v2 += __shfl_xor(v2, 4, 64);
          v2 += __shfl_xor(v2, 8, 64);
          red[r] = v2;
        }
        if (nlane == 0) {
#pragma unroll
          for (int r = 0; r < 4; ++r) {
            int b = g * MGRP + mt * 16 + quad * 4 + r;
            atomicAdd(out + (size_t)b * TSTEPS + t, red[r]);
          }
        }
      }
    }
  }
}

// ---------------------------------------------------------------------------
extern "C" void kernel_launch(void* const* d_in, const int* in_sizes, int n_in,
                              void* d_out, int out_size, void* d_ws, size_t ws_size,
                              hipStream_t stream) {
  const float* x    = (const float*)d_in[0];
  const float* Wih1 = (const float*)d_in[1];
  const float* Whh1 = (const float*)d_in[2];
  const float* bih1 = (const float*)d_in[3];
  const float* bhh1 = (const float*)d_in[4];
  const float* Wih2 = (const float*)d_in[5];
  const float* Whh2 = (const float*)d_in[6];
  const float* bih2 = (const float*)d_in[7];
  const float* bhh2 = (const float*)d_in[8];
  const float* Wlin = (const float*)d_in[9];
  const float* blin = (const float*)d_in[10];
  float* out = (float*)d_out;
  char* ws = (char*)d_ws;

  init_kernel<<<640, 256, 0, stream>>>(ws, out, blin);
  pack_kernel<<<1536, 256, 0, stream>>>(Whh1, Wih2, Whh2, ws);
  lstm_persist<<<256, 256, 0, stream>>>(x, Wih1, bih1, bhh1, bih2, bhh2, Wlin, out, ws);
}

// Round 6
// 4912.692 us; speedup vs baseline: 1.0721x; 1.0721x over previous
//
#include <hip/hip_runtime.h>
#include <hip/hip_fp16.h>

// ---------------------------------------------------------------------------
// 2-layer LSTM (T=512, B=128, H=512) + linear head, persistent-kernel design.
// Round 6: exact round-2 skeleton (best so far: shared per-step counter line,
// tid0/lane0 polling with s_sleep backoff, fire-and-forget atomicAdd release)
// plus ONLY two isolated changes:
//   (1) A-fragment ring loads batched into a[16] BEFORE the MFMA loop
//       (replaces 16 serial LLC round trips with one pipelined batch).
//   (2) linear head (shfl reduce + non-returning atomicAdd) moved AFTER the
//       end-of-step release -> off the recurrence critical path.
// ---------------------------------------------------------------------------

#define HDIM   512
#define TSTEPS 512
#define BATCH  128
#define DIN    5
#define NGRP   4
#define MGRP   32
#define NB1    16
#define NB2    32
#define RING   16

#define OFF_W1 0u            // packed layer1 weights: 16 blocks * 128KB = 2MB
#define OFF_W2 2097152u      // packed layer2 weights: 32 blocks * 128KB = 4MB
#define OFF_H1 6291456u      // h1 ring: 4 * 16 * 32 * 512 fp16 = 2MB
#define OFF_H2 8388608u      // h2 ring: 4 * 2 * 32 * 512 fp16 = 256KB
#define OFF_C1 8650752u      // cnt1: 4 * 512 u32
#define OFF_C2 8658944u      // cnt2: 4 * 512 u32
#define WS_END 8667136u

#define L1_HALF 31   // LDS-resident b-rows per hh half (of 64) in layer1
#define L2_HALF 27   // LDS-resident b-rows per kh half (of 64) in layer2

typedef _Float16 half8 __attribute__((ext_vector_type(8)));
typedef float    floatx4 __attribute__((ext_vector_type(4)));

__device__ __forceinline__ float sigf(float v) { return 1.0f / (1.0f + __expf(-v)); }

// 16B A-fragment read: two cache-bypassing relaxed 8B atomic loads (to LLC).
__device__ __forceinline__ half8 ring_ld16(const _Float16* p) {
  union { unsigned long long u[2]; half8 h; } r;
  unsigned long long* q = (unsigned long long*)p;
  r.u[0] = __hip_atomic_load(q,     __ATOMIC_RELAXED, __HIP_MEMORY_SCOPE_AGENT);
  r.u[1] = __hip_atomic_load(q + 1, __ATOMIC_RELAXED, __HIP_MEMORY_SCOPE_AGENT);
  return r.h;
}
__device__ __forceinline__ void ring_st8(_Float16* p, unsigned long long v) {
  __hip_atomic_store((unsigned long long*)p, v, __ATOMIC_RELAXED, __HIP_MEMORY_SCOPE_AGENT);
}
__device__ __forceinline__ void spin_ge(unsigned* p, unsigned tgt) {
  while (__hip_atomic_load(p, __ATOMIC_RELAXED, __HIP_MEMORY_SCOPE_AGENT) < tgt)
    __builtin_amdgcn_s_sleep(1);
}

// ---------------------------------------------------------------------------
extern "C" __global__ void init_kernel(char* __restrict__ ws, float* __restrict__ out,
                                       const float* __restrict__ blin) {
  unsigned tid = blockIdx.x * 256u + threadIdx.x;
  unsigned nz = (WS_END - OFF_H1) / 16u;
  if (tid < nz) ((uint4*)(ws + OFF_H1))[tid] = make_uint4(0, 0, 0, 0);
  if (tid < (unsigned)(BATCH * TSTEPS)) out[tid] = blin[0];
}

// Pack fp32 weights -> fp16 MFMA B-fragment layout.
// Layer1 block j: rows ordered [h(2)][gate(4)][ks(16)], row = 64 lanes * 16B.
//   col c = j*32 + h*16 + (lane&15), k = ks*32 + (lane>>4)*8 + e.
// Layer2 block j: rows ordered [kh(2)][gate(4)][ksl(16)];
//   c = j*16 + (lane&15), k' = kh*512 + ksl*32 + (lane>>4)*8 + e;
//   k'<512 -> W_ih2[k'], else W_hh2[k'-512].
extern "C" __global__ void pack_kernel(const float* __restrict__ Whh1,
                                       const float* __restrict__ Wih2,
                                       const float* __restrict__ Whh2,
                                       char* __restrict__ ws) {
  unsigned tid = blockIdx.x * 256u + threadIdx.x;
  const float* src;
  char* dst;
  if (tid < 131072u) {
    unsigned lane = tid & 63u, ks = (tid >> 6) & 15u, gg = (tid >> 10) & 3u,
             h = (tid >> 12) & 1u, j = tid >> 13;
    unsigned cg = j * 32u + h * 16u + (lane & 15u);
    unsigned row = gg * 512u + cg;
    unsigned k0 = ks * 32u + (lane >> 4) * 8u;
    src = Whh1 + (size_t)row * 512u + k0;
    dst = ws + OFF_W1 + (size_t)tid * 16u;
  } else {
    unsigned t2 = tid - 131072u;
    if (t2 >= 262144u) return;
    unsigned lane = t2 & 63u, ksl = (t2 >> 6) & 15u, gg = (t2 >> 10) & 3u,
             kh = (t2 >> 12) & 1u, j = t2 >> 13;
    unsigned cg = j * 16u + (lane & 15u);
    unsigned row = gg * 512u + cg;
    unsigned kp = kh * 512u + ksl * 32u + (lane >> 4) * 8u;
    src = (kp < 512u) ? (Wih2 + (size_t)row * 512u + kp)
                      : (Whh2 + (size_t)row * 512u + (kp - 512u));
    dst = ws + OFF_W2 + (size_t)t2 * 16u;
  }
  float4 lo = ((const float4*)src)[0];
  float4 hi = ((const float4*)src)[1];
  _Float16 v[8] = {(_Float16)lo.x, (_Float16)lo.y, (_Float16)lo.z, (_Float16)lo.w,
                   (_Float16)hi.x, (_Float16)hi.y, (_Float16)hi.z, (_Float16)hi.w};
  *(uint4*)dst = *(const uint4*)v;
}

// ---------------------------------------------------------------------------
extern "C" __global__ __launch_bounds__(256) void lstm_persist(
    const float* __restrict__ x,
    const float* __restrict__ Wih1,
    const float* __restrict__ bih1, const float* __restrict__ bhh1,
    const float* __restrict__ bih2, const float* __restrict__ bhh2,
    const float* __restrict__ Wlin,
    float* __restrict__ out,
    char* __restrict__ ws) {
  __shared__ char smem[65536];

  const int blk = blockIdx.x;
  const int xcd = blk & 7;
  const int slot = blk >> 3;
  const int tid = threadIdx.x;
  const int wave = tid >> 6;
  const int lane = tid & 63;
  const int nlane = lane & 15;
  const int quad = lane >> 4;

  _Float16* h1ring = (_Float16*)(ws + OFF_H1);
  _Float16* h2ring = (_Float16*)(ws + OFF_H2);
  unsigned* cnt1 = (unsigned*)(ws + OFF_C1);
  unsigned* cnt2 = (unsigned*)(ws + OFF_C2);

  if (xcd >= NGRP) {
    // ------------------------------ layer 1 -------------------------------
    const int g = xcd - NGRP;
    const int j = slot;
    if (j >= NB1) return;
    const char* gW = ws + OFF_W1 + (size_t)j * 131072u;
    {
      const uint4* s = (const uint4*)gW;
      uint4* d = (uint4*)smem;
      for (int i = tid; i < 62 * 64; i += 256) {
        int drow = i >> 6, c = i & 63;
        int srow = (drow < L1_HALF) ? drow : (64 + drow - L1_HALF);
        d[i] = s[srow * 64 + c];
      }
    }
    __syncthreads();
    _Float16* tile = (_Float16*)(smem + 63488);

    const int mt = wave >> 1;  // batch half (16 rows)
    const int hh = wave & 1;   // column half (16 cols)
    const int cg = j * 32 + hh * 16 + nlane;
    unsigned* myc1 = cnt1 + g * TSTEPS;
    unsigned* myc2 = cnt2 + g * TSTEPS;
    _Float16* ring = h1ring + (size_t)g * (RING * MGRP * HDIM);

    float bias_r[4], wih[4][5];
    for (int gg = 0; gg < 4; ++gg) {
      int row = gg * 512 + cg;
      bias_r[gg] = bih1[row] + bhh1[row];
      for (int k = 0; k < 5; ++k) wih[gg][k] = Wih1[row * 5 + k];
    }
    float cstate[4] = {};

    for (int t = 0; t < TSTEPS; ++t) {
      // batched A-fragment loads (32 independent 8B LLC loads -> pipeline)
      const _Float16* aprev =
          ring + (size_t)((t + RING - 1) % RING) * (MGRP * HDIM) +
          mt * 16 * HDIM + nlane * HDIM + quad * 8;
      half8 a[16];
#pragma unroll
      for (int ks = 0; ks < 16; ++ks) a[ks] = ring_ld16(aprev + ks * 32);

      // acc init = bias + x_t @ W_ih1^T (fp32, K=5) -- hides A-load latency
      float xr[4][5];
#pragma unroll
      for (int r = 0; r < 4; ++r) {
        int b = g * MGRP + mt * 16 + quad * 4 + r;
        const float* xp = x + ((size_t)t * BATCH + b) * DIN;
#pragma unroll
        for (int k = 0; k < 5; ++k) xr[r][k] = xp[k];
      }
      floatx4 acc[4];
#pragma unroll
      for (int gg = 0; gg < 4; ++gg) {
#pragma unroll
        for (int r = 0; r < 4; ++r) {
          float s = bias_r[gg];
#pragma unroll
          for (int k = 0; k < 5; ++k) s += xr[r][k] * wih[gg][k];
          acc[gg][r] = s;
        }
      }
#pragma unroll
      for (int ks = 0; ks < 16; ++ks) {
#pragma unroll
        for (int gg = 0; gg < 4; ++gg) {
          half8 b;
          if (gg * 16 + ks < L1_HALF)
            b = *(const half8*)(smem + ((hh * L1_HALF + gg * 16 + ks) * 64 + lane) * 16);
          else
            b = *(const half8*)(gW + (size_t)((hh * 64 + gg * 16 + ks) * 64 + lane) * 16);
          acc[gg] = __builtin_amdgcn_mfma_f32_16x16x32_f16(a[ks], b, acc[gg], 0, 0, 0);
        }
      }
      // gates -> LDS transpose tile (32 rows x 32 cols fp16)
#pragma unroll
      for (int r = 0; r < 4; ++r) {
        float iv = acc[0][r], fv = acc[1][r], gv = acc[2][r], ov = acc[3][r];
        float cn = sigf(fv) * cstate[r] + sigf(iv) * tanhf(gv);
        float hn = sigf(ov) * tanhf(cn);
        cstate[r] = cn;
        tile[(mt * 16 + quad * 4 + r) * 32 + hh * 16 + nlane] = (_Float16)hn;
      }
      __syncthreads();
      // ring store: 256 threads x 8B, coalesced, write-through to LLC
      {
        _Float16* hout = ring + (size_t)(t % RING) * (MGRP * HDIM);
        unsigned long long v =
            *(const unsigned long long*)(tile + (tid >> 3) * 32 + (tid & 7) * 4);
        ring_st8(hout + (tid >> 3) * HDIM + j * 32 + (tid & 7) * 4, v);
      }
      __syncthreads();  // drains vmcnt: all stores visible before release
      if (tid == 0) {
        __hip_atomic_fetch_add(&myc1[t], 1u, __ATOMIC_RELAXED, __HIP_MEMORY_SCOPE_AGENT);
        spin_ge(&myc1[t], NB1);
        // amortized ring back-pressure: allows writes t+1..t+8 (lead <= 9 < RING)
        if ((t & 7) == 7 && t >= 15) spin_ge(&myc2[t - 8], NB2);
      }
      __syncthreads();
      __asm__ __volatile__("" ::: "memory");
    }
  } else {
    // ------------------------------ layer 2 -------------------------------
    const int g = xcd;
    const int j = slot;
    const char* gW = ws + OFF_W2 + (size_t)j * 131072u;
    {
      const uint4* s = (const uint4*)gW;
      uint4* d = (uint4*)smem;
      for (int i = tid; i < 54 * 64; i += 256) {
        int drow = i >> 6, c = i & 63;
        int srow = (drow < L2_HALF) ? drow : (64 + drow - L2_HALF);
        d[i] = s[srow * 64 + c];
      }
    }
    __syncthreads();
    floatx4* pbase = (floatx4*)(smem + 55296);
    _Float16* tile2 = (_Float16*)(smem + 63488);

    const int kh = wave & 1;   // 0 -> h1(t) (W_ih2 half), 1 -> h2(t-1) (W_hh2 half)
    const int mt = wave >> 1;  // batch half
    const int cg = j * 16 + nlane;
    unsigned* myc1 = cnt1 + g * TSTEPS;
    unsigned* myc2 = cnt2 + g * TSTEPS;
    const _Float16* h1rd = h1ring + (size_t)g * (RING * MGRP * HDIM);
    _Float16* ring2 = h2ring + (size_t)g * (2 * MGRP * HDIM);

    float bias_r[4];
    for (int gg = 0; gg < 4; ++gg) {
      int row = gg * 512 + cg;
      bias_r[gg] = bih2[row] + bhh2[row];
    }
    const float wl = Wlin[cg];
    float cstate[4] = {};

    for (int t = 0; t < TSTEPS; ++t) {
      floatx4 acc[4];
#pragma unroll
      for (int gg = 0; gg < 4; ++gg)
        acc[gg] = (kh == 0)
            ? (floatx4){bias_r[gg], bias_r[gg], bias_r[gg], bias_r[gg]}
            : (floatx4){0.f, 0.f, 0.f, 0.f};
      if (kh == 0) {
        if (lane == 0) spin_ge(myc1 + t, NB1);  // wave-lockstep: whole wave waits
        __asm__ __volatile__("" ::: "memory");
      }
      const _Float16* abase = (kh == 0)
          ? h1rd + (size_t)(t % RING) * (MGRP * HDIM) + mt * 16 * HDIM
          : ring2 + (size_t)((t + 1) & 1) * (MGRP * HDIM) + mt * 16 * HDIM;
      // batched A-fragment loads (32 independent 8B LLC loads -> pipeline)
      half8 a[16];
#pragma unroll
      for (int ksl = 0; ksl < 16; ++ksl)
        a[ksl] = ring_ld16(abase + nlane * HDIM + ksl * 32 + quad * 8);
#pragma unroll
      for (int ksl = 0; ksl < 16; ++ksl) {
#pragma unroll
        for (int gg = 0; gg < 4; ++gg) {
          half8 b;
          if (gg * 16 + ksl < L2_HALF)
            b = *(const half8*)(smem + ((kh * L2_HALF + gg * 16 + ksl) * 64 + lane) * 16);
          else
            b = *(const half8*)(gW + (size_t)((kh * 64 + gg * 16 + ksl) * 64 + lane) * 16);
          acc[gg] = __builtin_amdgcn_mfma_f32_16x16x32_f16(a[ksl], b, acc[gg], 0, 0, 0);
        }
      }
      if (kh == 1) {
#pragma unroll
        for (int gg = 0; gg < 4; ++gg) pbase[(mt * 4 + gg) * 64 + lane] = acc[gg];
      }
      __syncthreads();
      float red[4];
      if (kh == 0) {
#pragma unroll
        for (int gg = 0; gg < 4; ++gg) acc[gg] += pbase[(mt * 4 + gg) * 64 + lane];
#pragma unroll
        for (int r = 0; r < 4; ++r) {
          float iv = acc[0][r], fv = acc[1][r], gv = acc[2][r], ov = acc[3][r];
          float cn = sigf(fv) * cstate[r] + sigf(iv) * tanhf(gv);
          float hn = sigf(ov) * tanhf(cn);
          cstate[r] = cn;
          tile2[(mt * 16 + quad * 4 + r) * 16 + nlane] = (_Float16)hn;
          red[r] = wl * hn;
        }
      }
      __syncthreads();
      if (tid < 128) {
        unsigned long long v =
            *(const unsigned long long*)(tile2 + (tid >> 2) * 16 + (tid & 3) * 4);
        ring_st8(ring2 + (size_t)(t & 1) * (MGRP * HDIM) + (tid >> 2) * HDIM +
                     j * 16 + (tid & 3) * 4, v);
      }
      __syncthreads();  // drains vmcnt before release
      if (tid == 0) {
        __hip_atomic_fetch_add(&myc2[t], 1u, __ATOMIC_RELAXED, __HIP_MEMORY_SCOPE_AGENT);
        spin_ge(&myc2[t], NB2);
      }
      __syncthreads();
      __asm__ __volatile__("" ::: "memory");
      // linear head: AFTER release, non-returning atomics (fire-and-forget,
      // off the recurrence critical path)
      if (kh == 0) {
#pragma unroll
        for (int r = 0; r < 4; ++r) {
          float v = red[r];
          v += __shfl_xor(v, 1, 64);
          v += __shfl_xor(v, 2, 64);
          v += __shfl_xor(v, 4, 64);
          v += __shfl_xor(v, 8, 64);
          red[r] = v;
        }
        if (nlane == 0) {
#pragma unroll
          for (int r = 0; r < 4; ++r) {
            int b = g * MGRP + mt * 16 + quad * 4 + r;
            atomicAdd(out + (size_t)b * TSTEPS + t, red[r]);
          }
        }
      }
    }
  }
}

// ---------------------------------------------------------------------------
extern "C" void kernel_launch(void* const* d_in, const int* in_sizes, int n_in,
                              void* d_out, int out_size, void* d_ws, size_t ws_size,
                              hipStream_t stream) {
  const float* x    = (const float*)d_in[0];
  const float* Wih1 = (const float*)d_in[1];
  const float* Whh1 = (const float*)d_in[2];
  const float* bih1 = (const float*)d_in[3];
  const float* bhh1 = (const float*)d_in[4];
  const float* Wih2 = (const float*)d_in[5];
  const float* Whh2 = (const float*)d_in[6];
  const float* bih2 = (const float*)d_in[7];
  const float* bhh2 = (const float*)d_in[8];
  const float* Wlin = (const float*)d_in[9];
  const float* blin = (const float*)d_in[10];
  float* out = (float*)d_out;
  char* ws = (char*)d_ws;

  init_kernel<<<640, 256, 0, stream>>>(ws, out, blin);
  pack_kernel<<<1536, 256, 0, stream>>>(Whh1, Wih2, Whh2, ws);
  lstm_persist<<<256, 256, 0, stream>>>(x, Wih1, bih1, bhh1, bih2, bhh2, Wlin, out, ws);
}

// Round 7
// 3516.386 us; speedup vs baseline: 1.4979x; 1.3971x over previous
//
#include <hip/hip_runtime.h>
#include <hip/hip_fp16.h>

// ---------------------------------------------------------------------------
// 2-layer LSTM (T=512, B=128, H=512) + linear head, persistent-kernel design.
// Round 7: persistent-RNN weights-in-registers.
//  - Each wave preloads its entire MFMA B-slice (64 rows x 16B/lane = 256
//    VGPRs) ONCE; the step loop's MFMA section is 100% register-fed (no LDS,
//    no global B). This removes the vmcnt in-order hazard that made batched
//    A-loads regress (fast B-loads queued behind slow uncached A-loads).
//  - A-fragment loads stay batched (32 independent 8B LLC loads, pipelined).
//  - Sync fabric = round-2's proven scheme verbatim: shared per-step counter,
//    tid0 fetch_add + spin (s_sleep backoff), end-of-step barrier.
//  - 1 block/CU enforced by VGPR usage (~390/wave -> 1 wave/SIMD).
// ---------------------------------------------------------------------------

#define HDIM   512
#define TSTEPS 512
#define BATCH  128
#define DIN    5
#define NGRP   4
#define MGRP   32
#define NB1    16
#define NB2    32
#define RING   16

#define OFF_W1 0u            // packed layer1 weights: 16 blocks * 128KB = 2MB
#define OFF_W2 2097152u      // packed layer2 weights: 32 blocks * 128KB = 4MB
#define OFF_H1 6291456u      // h1 ring: 4 * 16 * 32 * 512 fp16 = 2MB
#define OFF_H2 8388608u      // h2 ring: 4 * 2 * 32 * 512 fp16 = 256KB
#define OFF_C1 8650752u      // cnt1: 4 * 512 u32
#define OFF_C2 8658944u      // cnt2: 4 * 512 u32
#define WS_END 8667136u

typedef _Float16 half8 __attribute__((ext_vector_type(8)));
typedef float    floatx4 __attribute__((ext_vector_type(4)));

__device__ __forceinline__ float sigf(float v) { return 1.0f / (1.0f + __expf(-v)); }

// 16B A-fragment read: two cache-bypassing relaxed 8B atomic loads (to LLC).
__device__ __forceinline__ half8 ring_ld16(const _Float16* p) {
  union { unsigned long long u[2]; half8 h; } r;
  unsigned long long* q = (unsigned long long*)p;
  r.u[0] = __hip_atomic_load(q,     __ATOMIC_RELAXED, __HIP_MEMORY_SCOPE_AGENT);
  r.u[1] = __hip_atomic_load(q + 1, __ATOMIC_RELAXED, __HIP_MEMORY_SCOPE_AGENT);
  return r.h;
}
__device__ __forceinline__ void ring_st8(_Float16* p, unsigned long long v) {
  __hip_atomic_store((unsigned long long*)p, v, __ATOMIC_RELAXED, __HIP_MEMORY_SCOPE_AGENT);
}
__device__ __forceinline__ void spin_ge(unsigned* p, unsigned tgt) {
  while (__hip_atomic_load(p, __ATOMIC_RELAXED, __HIP_MEMORY_SCOPE_AGENT) < tgt)
    __builtin_amdgcn_s_sleep(1);
}

// ---------------------------------------------------------------------------
extern "C" __global__ void init_kernel(char* __restrict__ ws, float* __restrict__ out,
                                       const float* __restrict__ blin) {
  unsigned tid = blockIdx.x * 256u + threadIdx.x;
  unsigned nz = (WS_END - OFF_H1) / 16u;
  if (tid < nz) ((uint4*)(ws + OFF_H1))[tid] = make_uint4(0, 0, 0, 0);
  if (tid < (unsigned)(BATCH * TSTEPS)) out[tid] = blin[0];
}

// Pack fp32 weights -> fp16 MFMA B-fragment layout.
// Layer1 block j: rows ordered [h(2)][gate(4)][ks(16)], row = 64 lanes * 16B.
//   col c = j*32 + h*16 + (lane&15), k = ks*32 + (lane>>4)*8 + e.
// Layer2 block j: rows ordered [kh(2)][gate(4)][ksl(16)];
//   c = j*16 + (lane&15), k' = kh*512 + ksl*32 + (lane>>4)*8 + e;
//   k'<512 -> W_ih2[k'], else W_hh2[k'-512].
extern "C" __global__ void pack_kernel(const float* __restrict__ Whh1,
                                       const float* __restrict__ Wih2,
                                       const float* __restrict__ Whh2,
                                       char* __restrict__ ws) {
  unsigned tid = blockIdx.x * 256u + threadIdx.x;
  const float* src;
  char* dst;
  if (tid < 131072u) {
    unsigned lane = tid & 63u, ks = (tid >> 6) & 15u, gg = (tid >> 10) & 3u,
             h = (tid >> 12) & 1u, j = tid >> 13;
    unsigned cg = j * 32u + h * 16u + (lane & 15u);
    unsigned row = gg * 512u + cg;
    unsigned k0 = ks * 32u + (lane >> 4) * 8u;
    src = Whh1 + (size_t)row * 512u + k0;
    dst = ws + OFF_W1 + (size_t)tid * 16u;
  } else {
    unsigned t2 = tid - 131072u;
    if (t2 >= 262144u) return;
    unsigned lane = t2 & 63u, ksl = (t2 >> 6) & 15u, gg = (t2 >> 10) & 3u,
             kh = (t2 >> 12) & 1u, j = t2 >> 13;
    unsigned cg = j * 16u + (lane & 15u);
    unsigned row = gg * 512u + cg;
    unsigned kp = kh * 512u + ksl * 32u + (lane >> 4) * 8u;
    src = (kp < 512u) ? (Wih2 + (size_t)row * 512u + kp)
                      : (Whh2 + (size_t)row * 512u + (kp - 512u));
    dst = ws + OFF_W2 + (size_t)t2 * 16u;
  }
  float4 lo = ((const float4*)src)[0];
  float4 hi = ((const float4*)src)[1];
  _Float16 v[8] = {(_Float16)lo.x, (_Float16)lo.y, (_Float16)lo.z, (_Float16)lo.w,
                   (_Float16)hi.x, (_Float16)hi.y, (_Float16)hi.z, (_Float16)hi.w};
  *(uint4*)dst = *(const uint4*)v;
}

// ---------------------------------------------------------------------------
extern "C" __global__ __launch_bounds__(256, 1) void lstm_persist(
    const float* __restrict__ x,
    const float* __restrict__ Wih1,
    const float* __restrict__ bih1, const float* __restrict__ bhh1,
    const float* __restrict__ bih2, const float* __restrict__ bhh2,
    const float* __restrict__ Wlin,
    float* __restrict__ out,
    char* __restrict__ ws) {
  __shared__ char smem[16384];

  const int blk = blockIdx.x;
  const int xcd = blk & 7;
  const int slot = blk >> 3;
  const int tid = threadIdx.x;
  const int wave = tid >> 6;
  const int lane = tid & 63;
  const int nlane = lane & 15;
  const int quad = lane >> 4;

  _Float16* h1ring = (_Float16*)(ws + OFF_H1);
  _Float16* h2ring = (_Float16*)(ws + OFF_H2);
  unsigned* cnt1 = (unsigned*)(ws + OFF_C1);
  unsigned* cnt2 = (unsigned*)(ws + OFF_C2);

  if (xcd >= NGRP) {
    // ------------------------------ layer 1 -------------------------------
    const int g = xcd - NGRP;
    const int j = slot;
    if (j >= NB1) return;
    const char* gW = ws + OFF_W1 + (size_t)j * 131072u;

    const int mt = wave >> 1;  // batch half (16 rows)
    const int hh = wave & 1;   // column half (16 cols)
    const int cg = j * 32 + hh * 16 + nlane;
    unsigned* myc1 = cnt1 + g * TSTEPS;
    unsigned* myc2 = cnt2 + g * TSTEPS;
    _Float16* ring = h1ring + (size_t)g * (RING * MGRP * HDIM);
    _Float16* tile = (_Float16*)smem;  // 32x32 fp16 = 2KB

    // persistent B-slice: 64 rows x 16B/lane = 256 VGPRs, loaded once
    half8 breg[64];
#pragma unroll
    for (int r = 0; r < 64; ++r)
      breg[r] = *(const half8*)(gW + (size_t)((hh * 64 + r) * 64 + lane) * 16);

    float bias_r[4], wih[4][5];
    for (int gg = 0; gg < 4; ++gg) {
      int row = gg * 512 + cg;
      bias_r[gg] = bih1[row] + bhh1[row];
      for (int k = 0; k < 5; ++k) wih[gg][k] = Wih1[row * 5 + k];
    }
    float cstate[4] = {};

    for (int t = 0; t < TSTEPS; ++t) {
      // batched A-fragment loads (32 independent 8B LLC loads -> pipeline)
      const _Float16* aprev =
          ring + (size_t)((t + RING - 1) % RING) * (MGRP * HDIM) +
          mt * 16 * HDIM + nlane * HDIM + quad * 8;
      half8 a[16];
#pragma unroll
      for (int ks = 0; ks < 16; ++ks) a[ks] = ring_ld16(aprev + ks * 32);

      // acc init = bias + x_t @ W_ih1^T (fp32, K=5) -- overlaps A-load latency
      float xr[4][5];
#pragma unroll
      for (int r = 0; r < 4; ++r) {
        int b = g * MGRP + mt * 16 + quad * 4 + r;
        const float* xp = x + ((size_t)t * BATCH + b) * DIN;
#pragma unroll
        for (int k = 0; k < 5; ++k) xr[r][k] = xp[k];
      }
      floatx4 acc[4];
#pragma unroll
      for (int gg = 0; gg < 4; ++gg) {
#pragma unroll
        for (int r = 0; r < 4; ++r) {
          float s = bias_r[gg];
#pragma unroll
          for (int k = 0; k < 5; ++k) s += xr[r][k] * wih[gg][k];
          acc[gg][r] = s;
        }
      }
      // 64 register-fed MFMAs: no memory ops in this loop
#pragma unroll
      for (int ks = 0; ks < 16; ++ks) {
#pragma unroll
        for (int gg = 0; gg < 4; ++gg)
          acc[gg] = __builtin_amdgcn_mfma_f32_16x16x32_f16(a[ks], breg[gg * 16 + ks],
                                                           acc[gg], 0, 0, 0);
      }
      // gates -> LDS transpose tile (32 rows x 32 cols fp16)
#pragma unroll
      for (int r = 0; r < 4; ++r) {
        float iv = acc[0][r], fv = acc[1][r], gv = acc[2][r], ov = acc[3][r];
        float cn = sigf(fv) * cstate[r] + sigf(iv) * tanhf(gv);
        float hn = sigf(ov) * tanhf(cn);
        cstate[r] = cn;
        tile[(mt * 16 + quad * 4 + r) * 32 + hh * 16 + nlane] = (_Float16)hn;
      }
      __syncthreads();
      // ring store: 256 threads x 8B, coalesced, write-through to LLC
      {
        _Float16* hout = ring + (size_t)(t % RING) * (MGRP * HDIM);
        unsigned long long v =
            *(const unsigned long long*)(tile + (tid >> 3) * 32 + (tid & 7) * 4);
        ring_st8(hout + (tid >> 3) * HDIM + j * 32 + (tid & 7) * 4, v);
      }
      __syncthreads();  // drains vmcnt: all stores visible before release
      if (tid == 0) {
        __hip_atomic_fetch_add(&myc1[t], 1u, __ATOMIC_RELAXED, __HIP_MEMORY_SCOPE_AGENT);
        spin_ge(&myc1[t], NB1);
        // amortized ring back-pressure: allows writes t+1..t+8 (lead <= 9 < RING)
        if ((t & 7) == 7 && t >= 15) spin_ge(&myc2[t - 8], NB2);
      }
      __syncthreads();
      __asm__ __volatile__("" ::: "memory");
    }
  } else {
    // ------------------------------ layer 2 -------------------------------
    const int g = xcd;
    const int j = slot;
    const char* gW = ws + OFF_W2 + (size_t)j * 131072u;

    const int kh = wave & 1;   // 0 -> h1(t) (W_ih2 half), 1 -> h2(t-1) (W_hh2 half)
    const int mt = wave >> 1;  // batch half
    const int cg = j * 16 + nlane;
    unsigned* myc1 = cnt1 + g * TSTEPS;
    unsigned* myc2 = cnt2 + g * TSTEPS;
    const _Float16* h1rd = h1ring + (size_t)g * (RING * MGRP * HDIM);
    _Float16* ring2 = h2ring + (size_t)g * (2 * MGRP * HDIM);
    floatx4* pbase = (floatx4*)smem;                 // 8KB
    _Float16* tile2 = (_Float16*)(smem + 8192);      // 32x16 fp16 = 1KB

    // persistent B-slice: 64 rows x 16B/lane = 256 VGPRs, loaded once
    half8 breg[64];
#pragma unroll
    for (int r = 0; r < 64; ++r)
      breg[r] = *(const half8*)(gW + (size_t)((kh * 64 + r) * 64 + lane) * 16);

    float bias_r[4];
    for (int gg = 0; gg < 4; ++gg) {
      int row = gg * 512 + cg;
      bias_r[gg] = bih2[row] + bhh2[row];
    }
    const float wl = Wlin[cg];
    float cstate[4] = {};

    for (int t = 0; t < TSTEPS; ++t) {
      floatx4 acc[4];
#pragma unroll
      for (int gg = 0; gg < 4; ++gg)
        acc[gg] = (kh == 0)
            ? (floatx4){bias_r[gg], bias_r[gg], bias_r[gg], bias_r[gg]}
            : (floatx4){0.f, 0.f, 0.f, 0.f};
      if (kh == 0) {
        if (lane == 0) spin_ge(myc1 + t, NB1);  // wave-lockstep: whole wave waits
        __asm__ __volatile__("" ::: "memory");
      }
      const _Float16* abase = (kh == 0)
          ? h1rd + (size_t)(t % RING) * (MGRP * HDIM) + mt * 16 * HDIM
          : ring2 + (size_t)((t + 1) & 1) * (MGRP * HDIM) + mt * 16 * HDIM;
      // batched A-fragment loads (32 independent 8B LLC loads -> pipeline)
      half8 a[16];
#pragma unroll
      for (int ksl = 0; ksl < 16; ++ksl)
        a[ksl] = ring_ld16(abase + nlane * HDIM + ksl * 32 + quad * 8);
      // 64 register-fed MFMAs: no memory ops in this loop
#pragma unroll
      for (int ksl = 0; ksl < 16; ++ksl) {
#pragma unroll
        for (int gg = 0; gg < 4; ++gg)
          acc[gg] = __builtin_amdgcn_mfma_f32_16x16x32_f16(a[ksl], breg[gg * 16 + ksl],
                                                           acc[gg], 0, 0, 0);
      }
      if (kh == 1) {
#pragma unroll
        for (int gg = 0; gg < 4; ++gg) pbase[(mt * 4 + gg) * 64 + lane] = acc[gg];
      }
      __syncthreads();
      float red[4];
      if (kh == 0) {
#pragma unroll
        for (int gg = 0; gg < 4; ++gg) acc[gg] += pbase[(mt * 4 + gg) * 64 + lane];
#pragma unroll
        for (int r = 0; r < 4; ++r) {
          float iv = acc[0][r], fv = acc[1][r], gv = acc[2][r], ov = acc[3][r];
          float cn = sigf(fv) * cstate[r] + sigf(iv) * tanhf(gv);
          float hn = sigf(ov) * tanhf(cn);
          cstate[r] = cn;
          tile2[(mt * 16 + quad * 4 + r) * 16 + nlane] = (_Float16)hn;
          red[r] = wl * hn;
        }
      }
      __syncthreads();
      if (tid < 128) {
        unsigned long long v =
            *(const unsigned long long*)(tile2 + (tid >> 2) * 16 + (tid & 3) * 4);
        ring_st8(ring2 + (size_t)(t & 1) * (MGRP * HDIM) + (tid >> 2) * HDIM +
                     j * 16 + (tid & 3) * 4, v);
      }
      __syncthreads();  // drains vmcnt before release
      if (tid == 0) {
        __hip_atomic_fetch_add(&myc2[t], 1u, __ATOMIC_RELAXED, __HIP_MEMORY_SCOPE_AGENT);
        spin_ge(&myc2[t], NB2);
      }
      __syncthreads();
      __asm__ __volatile__("" ::: "memory");
      // linear head: AFTER release, fire-and-forget (off the critical path)
      if (kh == 0) {
#pragma unroll
        for (int r = 0; r < 4; ++r) {
          float v = red[r];
          v += __shfl_xor(v, 1, 64);
          v += __shfl_xor(v, 2, 64);
          v += __shfl_xor(v, 4, 64);
          v += __shfl_xor(v, 8, 64);
          red[r] = v;
        }
        if (nlane == 0) {
#pragma unroll
          for (int r = 0; r < 4; ++r) {
            int b = g * MGRP + mt * 16 + quad * 4 + r;
            atomicAdd(out + (size_t)b * TSTEPS + t, red[r]);
          }
        }
      }
    }
  }
}

// ---------------------------------------------------------------------------
extern "C" void kernel_launch(void* const* d_in, const int* in_sizes, int n_in,
                              void* d_out, int out_size, void* d_ws, size_t ws_size,
                              hipStream_t stream) {
  const float* x    = (const float*)d_in[0];
  const float* Wih1 = (const float*)d_in[1];
  const float* Whh1 = (const float*)d_in[2];
  const float* bih1 = (const float*)d_in[3];
  const float* bhh1 = (const float*)d_in[4];
  const float* Wih2 = (const float*)d_in[5];
  const float* Whh2 = (const float*)d_in[6];
  const float* bih2 = (const float*)d_in[7];
  const float* bhh2 = (const float*)d_in[8];
  const float* Wlin = (const float*)d_in[9];
  const float* blin = (const float*)d_in[10];
  float* out = (float*)d_out;
  char* ws = (char*)d_ws;

  init_kernel<<<640, 256, 0, stream>>>(ws, out, blin);
  pack_kernel<<<1536, 256, 0, stream>>>(Whh1, Wih2, Whh2, ws);
  lstm_persist<<<256, 256, 0, stream>>>(x, Wih1, bih1, bhh1, bih2, bhh2, Wlin, out, ws);
}